// Round 6
// baseline (474.588 us; speedup 1.0000x reference)
//
#include <hip/hip_runtime.h>
#include <hip/hip_bf16.h>

// Problem constants
#define BB   128
#define NN   196
#define MM   (BB*NN)      // 25088
#define ENC  2048
#define ATT  512
#define DEC  512
#define BK   32
#define KSTEPS (ENC/BK)   // 64
#define MTILES (MM/64)    // 392

using f32x4 = __attribute__((ext_vector_type(4))) float;
using s16x8 = __attribute__((ext_vector_type(8))) short;
using u16x8 = __attribute__((ext_vector_type(8))) unsigned short;

__device__ __forceinline__ short f2bf(float f) {
    union { __hip_bfloat16 h; short s; } u;
    u.h = __float2bfloat16(f);
    return u.s;
}

// ---------------------------------------------------------------------------
// k0a: transpose+convert W_enc [2048][512] f32 -> Wt [512][2048] bf16
// ---------------------------------------------------------------------------
__global__ void transpose_convert_kernel(const float* __restrict__ W,
                                         unsigned short* __restrict__ Wt) {
    __shared__ float tile[32][33];
    const int a0 = blockIdx.x * 32;
    const int k0 = blockIdx.y * 32;
    const int tx = threadIdx.x & 31, ty = threadIdx.x >> 5;
    #pragma unroll
    for (int i = 0; i < 32; i += 8)
        tile[ty + i][tx] = W[(size_t)(k0 + ty + i) * ATT + a0 + tx];
    __syncthreads();
    #pragma unroll
    for (int i = 0; i < 32; i += 8) {
        union { __hip_bfloat16 h; unsigned short u; } v;
        v.h = __float2bfloat16(tile[tx][ty + i]);
        Wt[(size_t)(a0 + ty + i) * ENC + k0 + tx] = v.u;
    }
}

// ---------------------------------------------------------------------------
// k0c: pack encoder fp32 [MM][ENC] -> bf16 K-panels encp[ks][mt][row64][kk32]
//   Read: row-linear 8KB bursts. GEMM then reads each panel as one 4KB
//   contiguous chunk -> DRAM-friendly, L3-hot (1.6 MB global set per step).
// ---------------------------------------------------------------------------
__global__ __launch_bounds__(256)
void enc_pack_kernel(const float* __restrict__ enc,
                     unsigned short* __restrict__ encp) {
    const int mt   = blockIdx.x;        // 392
    const int half = blockIdx.y;        // 0..1 -> rows 0-31 / 32-63
    const int t = threadIdx.x;
    const int ks = t >> 2, kk0 = (t & 3) * 8;   // t*8 = ks*32 + kk0
    #pragma unroll 4
    for (int i = 0; i < 32; ++i) {
        int row = half * 32 + i;
        const float* in = enc + ((size_t)mt * 64 + row) * ENC + t * 8;
        f32x4 a = *(const f32x4*)in;
        f32x4 b = *(const f32x4*)(in + 4);
        u16x8 o;
        #pragma unroll
        for (int j = 0; j < 4; ++j) {
            o[j]     = (unsigned short)f2bf(a[j]);
            o[4 + j] = (unsigned short)f2bf(b[j]);
        }
        *(u16x8*)(encp + ((size_t)(ks * MTILES + mt) * 64 + row) * 32 + kk0) = o;
    }
}

// ---------------------------------------------------------------------------
// k0b: att2[b][a] = dec[b] @ W_dec[:,a] + b_dec[a] + b_enc[a]
// ---------------------------------------------------------------------------
__global__ void att2_kernel(const float* __restrict__ dec,
                            const float* __restrict__ Wd,
                            const float* __restrict__ bd,
                            const float* __restrict__ benc,
                            float* __restrict__ att2) {
    const int b  = blockIdx.x;
    const int c0 = blockIdx.y * 64;
    const int t  = threadIdx.x;
    const int cl = t & 63, kg = t >> 6;
    __shared__ float sdec[DEC];
    __shared__ float red[4][64];
    sdec[t]       = dec[b * DEC + t];
    sdec[t + 256] = dec[b * DEC + t + 256];
    __syncthreads();
    float acc = 0.f;
    const float* wp = Wd + c0 + cl;
    #pragma unroll 8
    for (int k = kg * 128; k < kg * 128 + 128; ++k)
        acc += sdec[k] * wp[(size_t)k * ATT];
    red[kg][cl] = acc;
    __syncthreads();
    if (t < 64) {
        float s = red[0][t] + red[1][t] + red[2][t] + red[3][t];
        att2[b * ATT + c0 + t] = s + bd[c0 + t] + benc[c0 + t];
    }
}

// ---------------------------------------------------------------------------
// k1 MAIN: fused GEMM + bias + relu + dot(W_full) -> e_part[2][MM]
//   A from packed K-panels: ONE 4KB contiguous DMA per block-step (linear
//   in t). B from L2-resident Wt. 8 ds_read_b128 + 16 MFMA per wave-step.
// ---------------------------------------------------------------------------
__global__ __launch_bounds__(256, 4)
void gemm_bf16_kernel(const unsigned short* __restrict__ encp,
                      const unsigned short* __restrict__ Wt,
                      const float* __restrict__ att2,
                      const float* __restrict__ Wf,
                      float* __restrict__ e_part) {
    __shared__ unsigned short sA[64 * 32];    // 4 KB, [row][kk] 64B rows
    __shared__ unsigned short sB[256 * 32];   // 16 KB, 64B rows
    __shared__ float e_sm[64];

    const int t    = threadIdx.x;
    const int lane = t & 63;
    const int w    = t >> 6;
    const int aBlk  = blockIdx.x;          // 0..1 (fastest)
    const int mt    = blockIdx.y;          // 392
    const int mBase = mt * 64;
    const int aBase = aBlk * 256;
    const int r = lane & 15, q = lane >> 4;

    // A staging: panel (ks*392+mt) is 4KB contiguous; thread t takes 16B at t*16
    const unsigned short* gA = encp + (size_t)mt * 2048 + t * 8;
    const unsigned short* gB[4];
    #pragma unroll
    for (int i = 0; i < 4; ++i) {
        int s = i * 256 + t;
        gB[i] = Wt + (size_t)(aBase + (s >> 2)) * ENC + (s & 3) * 8;
    }

    int offA[4];
    #pragma unroll
    for (int mi = 0; mi < 4; ++mi)
        offA[mi] = (mi * 16 + r) * 64 + q * 16;
    int offB[4];
    #pragma unroll
    for (int ni = 0; ni < 4; ++ni)
        offB[ni] = (w * 64 + ni * 16 + r) * 64 + q * 16;

    f32x4 acc[4][4] = {};

    #pragma unroll 1
    for (int ks = 0; ks < KSTEPS; ++ks) {
        __builtin_amdgcn_global_load_lds(
            (const __attribute__((address_space(1))) void*)(gA + (size_t)ks * MTILES * 2048),
            (__attribute__((address_space(3))) void*)((char*)sA + t * 16),
            16, 0, 0);
        #pragma unroll
        for (int i = 0; i < 4; ++i)
            __builtin_amdgcn_global_load_lds(
                (const __attribute__((address_space(1))) void*)(gB[i] + (size_t)ks * BK),
                (__attribute__((address_space(3))) void*)((char*)sB + (i * 256 + t) * 16),
                16, 0, 0);
        __syncthreads();

        s16x8 af[4], bf[4];
        #pragma unroll
        for (int mi = 0; mi < 4; ++mi)
            af[mi] = *(const s16x8*)((const char*)sA + offA[mi]);
        #pragma unroll
        for (int ni = 0; ni < 4; ++ni)
            bf[ni] = *(const s16x8*)((const char*)sB + offB[ni]);

        #pragma unroll
        for (int mi = 0; mi < 4; ++mi)
            #pragma unroll
            for (int ni = 0; ni < 4; ++ni)
                acc[mi][ni] = __builtin_amdgcn_mfma_f32_16x16x32_bf16(
                    af[mi], bf[ni], acc[mi][ni], 0, 0, 0);
        __syncthreads();
    }

    // --- epilogue: e contribution = sum_a relu(att1 + att2) * Wf ---
    if (t < 64) e_sm[t] = 0.f;
    __syncthreads();

    float wfv[4];
    #pragma unroll
    for (int ni = 0; ni < 4; ++ni)
        wfv[ni] = Wf[aBase + w * 64 + ni * 16 + r];

    #pragma unroll
    for (int mi = 0; mi < 4; ++mi) {
        #pragma unroll
        for (int reg = 0; reg < 4; ++reg) {
            int lrow = mi * 16 + q * 4 + reg;       // C/D: row=(lane>>4)*4+reg
            int gm = mBase + lrow;
            int b = gm / NN;
            const float* a2 = att2 + b * ATT + aBase + w * 64;
            float rs = 0.f;
            #pragma unroll
            for (int ni = 0; ni < 4; ++ni) {
                float v = acc[mi][ni][reg] + a2[ni * 16 + r];  // col = lane&15
                rs += fmaxf(v, 0.f) * wfv[ni];
            }
            rs += __shfl_xor(rs, 1);
            rs += __shfl_xor(rs, 2);
            rs += __shfl_xor(rs, 4);
            rs += __shfl_xor(rs, 8);
            if (r == 0) atomicAdd(&e_sm[lrow], rs);
        }
    }
    __syncthreads();
    if (t < 64)
        e_part[(size_t)aBlk * MM + mBase + t] = e_sm[t];
}

// ---------------------------------------------------------------------------
// k1 FALLBACK (R4, proven): 64m x 128a fp32-A gemm -> e_part[4][MM]
// ---------------------------------------------------------------------------
__global__ __launch_bounds__(256, 5)
void gemm_e_kernel(const float* __restrict__ enc,
                   const unsigned short* __restrict__ Wt,
                   const float* __restrict__ att2,
                   const float* __restrict__ Wf,
                   float* __restrict__ e_part) {
    __shared__ float sA[64 * 32];
    __shared__ unsigned short sB[128 * 32];
    __shared__ float e_sm[64];

    const int t    = threadIdx.x;
    const int lane = t & 63;
    const int w    = t >> 6;
    const int aBlk  = blockIdx.x;
    const int mBase = blockIdx.y * 64;
    const int aBase = aBlk * 128;
    const int r = lane & 15, q = lane >> 4;

    const float* gA[2];
    #pragma unroll
    for (int i = 0; i < 2; ++i) {
        int s = i * 256 + t;
        int row = s >> 3, ck = s & 7;
        int g = ck ^ (row & 7);
        gA[i] = enc + (size_t)(mBase + row) * ENC + g * 4;
    }
    const unsigned short* gB[2];
    #pragma unroll
    for (int i = 0; i < 2; ++i) {
        int s = i * 256 + t;
        int row = s >> 2, ck = s & 3;
        int g = ck ^ ((row & 3) ^ ((row >> 2) & 3));
        gB[i] = Wt + (size_t)(aBase + row) * ENC + g * 8;
    }

    int offA[4][2];
    #pragma unroll
    for (int mi = 0; mi < 4; ++mi) {
        int row = mi * 16 + r;
        offA[mi][0] = row * 128 + ((2 * q)     ^ (row & 7)) * 16;
        offA[mi][1] = row * 128 + ((2 * q + 1) ^ (row & 7)) * 16;
    }
    int offB[2];
    #pragma unroll
    for (int ni = 0; ni < 2; ++ni) {
        int col = w * 32 + ni * 16 + r;
        offB[ni] = col * 64 + (q ^ ((col & 3) ^ ((col >> 2) & 3))) * 16;
    }

    f32x4 acc[4][2] = {};

    #pragma unroll 1
    for (int ks = 0; ks < KSTEPS; ++ks) {
        #pragma unroll
        for (int i = 0; i < 2; ++i)
            __builtin_amdgcn_global_load_lds(
                (const __attribute__((address_space(1))) void*)(gA[i] + (size_t)ks * BK),
                (__attribute__((address_space(3))) void*)((char*)sA + (i * 256 + w * 64) * 16),
                16, 0, 0);
        #pragma unroll
        for (int i = 0; i < 2; ++i)
            __builtin_amdgcn_global_load_lds(
                (const __attribute__((address_space(1))) void*)(gB[i] + (size_t)ks * BK),
                (__attribute__((address_space(3))) void*)((char*)sB + (i * 256 + w * 64) * 16),
                16, 0, 0);
        __syncthreads();

        s16x8 af[4], bf[2];
        #pragma unroll
        for (int mi = 0; mi < 4; ++mi) {
            f32x4 f0 = *(const f32x4*)((const char*)sA + offA[mi][0]);
            f32x4 f1 = *(const f32x4*)((const char*)sA + offA[mi][1]);
            s16x8 a;
            #pragma unroll
            for (int j = 0; j < 4; ++j) { a[j] = f2bf(f0[j]); a[4 + j] = f2bf(f1[j]); }
            af[mi] = a;
        }
        #pragma unroll
        for (int ni = 0; ni < 2; ++ni)
            bf[ni] = *(const s16x8*)((const char*)sB + offB[ni]);

        #pragma unroll
        for (int mi = 0; mi < 4; ++mi)
            #pragma unroll
            for (int ni = 0; ni < 2; ++ni)
                acc[mi][ni] = __builtin_amdgcn_mfma_f32_16x16x32_bf16(
                    af[mi], bf[ni], acc[mi][ni], 0, 0, 0);
        __syncthreads();
    }

    if (t < 64) e_sm[t] = 0.f;
    __syncthreads();

    float wfv[2];
    #pragma unroll
    for (int ni = 0; ni < 2; ++ni)
        wfv[ni] = Wf[aBase + w * 32 + ni * 16 + r];

    #pragma unroll
    for (int mi = 0; mi < 4; ++mi) {
        #pragma unroll
        for (int reg = 0; reg < 4; ++reg) {
            int lrow = mi * 16 + q * 4 + reg;
            int gm = mBase + lrow;
            int b = gm / NN;
            const float* a2 = att2 + b * ATT + aBase + w * 32;
            float rs = 0.f;
            #pragma unroll
            for (int ni = 0; ni < 2; ++ni) {
                float v = acc[mi][ni][reg] + a2[ni * 16 + r];
                rs += fmaxf(v, 0.f) * wfv[ni];
            }
            rs += __shfl_xor(rs, 1);
            rs += __shfl_xor(rs, 2);
            rs += __shfl_xor(rs, 4);
            rs += __shfl_xor(rs, 8);
            if (r == 0) atomicAdd(&e_sm[lrow], rs);
        }
    }
    __syncthreads();
    if (t < 64)
        e_part[(size_t)aBlk * MM + mBase + t] = e_sm[t];
}

// ---------------------------------------------------------------------------
// k2a: softmax over N per batch -> alpha (out tail + ws copy); nparts variable
// ---------------------------------------------------------------------------
__global__ void softmax_kernel(const float* __restrict__ e_part,
                               const float* __restrict__ b_full,
                               float* __restrict__ out,
                               float* __restrict__ alpha_ws,
                               int nparts) {
    const int b = blockIdx.x;
    const int t = threadIdx.x;      // 256
    __shared__ float sm[256];

    float v = -3.0e38f;
    if (t < NN) {
        int gm = b * NN + t;
        float s = b_full[0];
        for (int p = 0; p < nparts; ++p) s += e_part[(size_t)p * MM + gm];
        v = s;
    }
    sm[t] = v;
    __syncthreads();
    for (int s = 128; s > 0; s >>= 1) {
        if (t < s) sm[t] = fmaxf(sm[t], sm[t + s]);
        __syncthreads();
    }
    float mx = sm[0];
    __syncthreads();
    float ex = (t < NN) ? __expf(v - mx) : 0.f;
    sm[t] = ex;
    __syncthreads();
    for (int s = 128; s > 0; s >>= 1) {
        if (t < s) sm[t] += sm[t + s];
        __syncthreads();
    }
    float inv = 1.0f / sm[0];
    if (t < NN) {
        float a = ex * inv;
        out[BB * ENC + b * NN + t] = a;
        alpha_ws[b * NN + t] = a;
    }
}

// ---------------------------------------------------------------------------
// k2b: awe[b][c] = sum_n enc[b][n][c] * alpha[b][n]   (fp32 enc, 4KB bursts)
// ---------------------------------------------------------------------------
__global__ __launch_bounds__(256)
void awe_kernel(const float* __restrict__ enc,
                const float* __restrict__ alpha_ws,
                float* __restrict__ out) {
    const int b = blockIdx.x, chunk = blockIdx.y;
    const int t = threadIdx.x;
    __shared__ float al[NN];
    if (t < NN) al[t] = alpha_ws[b * NN + t];
    __syncthreads();

    const float* ep = enc + (size_t)b * NN * ENC + chunk * 1024 + t * 4;
    f32x4 acc0 = {}, acc1 = {}, acc2 = {}, acc3 = {};
    #pragma unroll 2
    for (int n = 0; n < NN; n += 4) {   // 196 = 4*49 exact
        f32x4 v0 = *(const f32x4*)(ep + (size_t)(n + 0) * ENC);
        f32x4 v1 = *(const f32x4*)(ep + (size_t)(n + 1) * ENC);
        f32x4 v2 = *(const f32x4*)(ep + (size_t)(n + 2) * ENC);
        f32x4 v3 = *(const f32x4*)(ep + (size_t)(n + 3) * ENC);
        acc0 += v0 * al[n];
        acc1 += v1 * al[n + 1];
        acc2 += v2 * al[n + 2];
        acc3 += v3 * al[n + 3];
    }
    f32x4 s = (acc0 + acc1) + (acc2 + acc3);
    *(f32x4*)(out + (size_t)b * ENC + chunk * 1024 + t * 4) = s;
}

// ---------------------------------------------------------------------------
extern "C" void kernel_launch(void* const* d_in, const int* in_sizes, int n_in,
                              void* d_out, int out_size, void* d_ws, size_t ws_size,
                              hipStream_t stream) {
    const float* enc    = (const float*)d_in[0];
    const float* dec    = (const float*)d_in[1];
    const float* W_enc  = (const float*)d_in[2];
    const float* b_enc  = (const float*)d_in[3];
    const float* W_dec  = (const float*)d_in[4];
    const float* b_dec  = (const float*)d_in[5];
    const float* W_full = (const float*)d_in[6];
    const float* b_full = (const float*)d_in[7];
    float* out = (float*)d_out;   // [128*2048 awe | 128*196 alpha]

    char* ws = (char*)d_ws;
    unsigned short* Wt = (unsigned short*)ws;                        // 2 MB
    float* att2     = (float*)(ws + 2097152);                        // 256 KB
    float* e_part   = (float*)(ws + 2359296);                        // 4*MM*4 = 392 KB
    float* alpha_ws = (float*)(ws + 2760704);                        // 98 KB
    unsigned short* encp = (unsigned short*)(ws + 3145728);          // 98 MB (K-panels)
    const size_t WS_NEED = 3145728 + (size_t)MM * ENC * 2;           // ~101 MB

    transpose_convert_kernel<<<dim3(ATT / 32, ENC / 32), 256, 0, stream>>>(W_enc, Wt);
    att2_kernel<<<dim3(BB, 8), 256, 0, stream>>>(dec, W_dec, b_dec, b_enc, att2);

    if (ws_size >= WS_NEED) {
        enc_pack_kernel<<<dim3(MTILES, 2), 256, 0, stream>>>(enc, encp);
        gemm_bf16_kernel<<<dim3(2, MTILES), 256, 0, stream>>>(encp, Wt, att2, W_full, e_part);
        softmax_kernel<<<BB, 256, 0, stream>>>(e_part, b_full, out, alpha_ws, 2);
    } else {
        gemm_e_kernel<<<dim3(4, MTILES), 256, 0, stream>>>(enc, Wt, att2, W_full, e_part);
        softmax_kernel<<<BB, 256, 0, stream>>>(e_part, b_full, out, alpha_ws, 4);
    }
    awe_kernel<<<dim3(BB, 2), 256, 0, stream>>>(enc, alpha_ws, out);
}